// Round 2
// baseline (44.653 us; speedup 1.0000x reference)
//
#include <hip/hip_runtime.h>

// L=32768, N=32, E=H=1, BS=256 -> 128 blocks x 32 batches = 4096 rank-1
// softmax problems. s_ij = a_i * k_j (scale=1), out_i = sum p_ij v_j / sum p_ij.
// One 128-thread workgroup per problem; each thread owns rows tid and tid+128.

#define LL   32768
#define NN   32
#define BSZ  256
#define NBLK (LL / BSZ)
#define LOG2E 1.4426950408889634f

__global__ __launch_bounds__(128, 4) void BlockCrossAttn_kernel(
    const float* __restrict__ q_in, const float* __restrict__ k_in,
    const float* __restrict__ v_in,
    const float* __restrict__ ipw,  const float* __restrict__ ipb,
    const float* __restrict__ opw,  const float* __restrict__ opb,
    float* __restrict__ out)
{
    const int blk = blockIdx.x >> 5;   // block index b in [0,128)
    const int n   = blockIdx.x & 31;   // batch index
    const int tid = threadIdx.x;       // 0..127

    const float wq = ipw[0], wk = ipw[1], wv = ipw[2];
    const float bq = ipb[0], bk = ipb[1], bv = ipb[2];
    const float wo = opw[0], bo = opb[0];

    __shared__ alignas(16) float2 skv[BSZ];  // (k_j, v_j) interleaved
    __shared__ float sred[4];

    const int g0 = (blk * BSZ + tid) * NN + n;
    const int g1 = g0 + 128 * NN;

    const float qa = q_in[g0], qb = q_in[g1];
    const float ka = k_in[g0], kb = k_in[g1];
    const float va = v_in[g0], vb = v_in[g1];

    const float a0 = fmaf(qa, wq, bq) * LOG2E;   // log2-domain row coeff
    const float a1 = fmaf(qb, wq, bq) * LOG2E;
    const float kp0 = fmaf(ka, wk, bk), kp1 = fmaf(kb, wk, bk);
    const float vp0 = fmaf(va, wv, bv), vp1 = fmaf(vb, wv, bv);
    skv[tid]       = make_float2(kp0, vp0);
    skv[tid + 128] = make_float2(kp1, vp1);

    // block kmax/kmin -> row max m_i = max(a_i*kmx, a_i*kmn), in log2 domain
    float kmx = fmaxf(kp0, kp1), kmn = fminf(kp0, kp1);
    #pragma unroll
    for (int off = 32; off >= 1; off >>= 1) {
        kmx = fmaxf(kmx, __shfl_xor(kmx, off));
        kmn = fminf(kmn, __shfl_xor(kmn, off));
    }
    const int wid = tid >> 6;          // 2 waves
    if ((tid & 63) == 0) { sred[wid] = kmx; sred[2 + wid] = kmn; }
    __syncthreads();                   // also publishes skv
    kmx = fmaxf(sred[0], sred[1]);
    kmn = fminf(sred[2], sred[3]);

    const float m0 = fmaxf(a0 * kmx, a0 * kmn);
    const float m1 = fmaxf(a1 * kmx, a1 * kmn);

    // 8 independent accumulator chains: 2 rows x {even,odd} x {den,num}
    float d0a = 0.f, d0b = 0.f, d1a = 0.f, d1b = 0.f;
    float n0a = 0.f, n0b = 0.f, n1a = 0.f, n1b = 0.f;

    const float4* s4 = (const float4*)skv;   // (k0,v0,k1,v1) per entry
    #pragma unroll 8
    for (int jj = 0; jj < BSZ / 2; ++jj) {
        const float4 kv = s4[jj];
        const float p0a = __builtin_amdgcn_exp2f(fmaf(a0, kv.x, -m0));
        const float p0b = __builtin_amdgcn_exp2f(fmaf(a0, kv.z, -m0));
        const float p1a = __builtin_amdgcn_exp2f(fmaf(a1, kv.x, -m1));
        const float p1b = __builtin_amdgcn_exp2f(fmaf(a1, kv.z, -m1));
        d0a += p0a; d0b += p0b; d1a += p1a; d1b += p1b;
        n0a = fmaf(p0a, kv.y, n0a); n0b = fmaf(p0b, kv.w, n0b);
        n1a = fmaf(p1a, kv.y, n1a); n1b = fmaf(p1b, kv.w, n1b);
    }

    const float o0 = (n0a + n0b) / (d0a + d0b);
    const float o1 = (n1a + n1b) / (d1a + d1b);
    out[g0] = fmaf(o0, wo, bo);
    out[g1] = fmaf(o1, wo, bo);
}

extern "C" void kernel_launch(void* const* d_in, const int* in_sizes, int n_in,
                              void* d_out, int out_size, void* d_ws, size_t ws_size,
                              hipStream_t stream) {
    const float* q   = (const float*)d_in[0];
    const float* k   = (const float*)d_in[1];
    const float* v   = (const float*)d_in[2];
    const float* ipw = (const float*)d_in[3];
    const float* ipb = (const float*)d_in[4];
    const float* opw = (const float*)d_in[5];
    const float* opb = (const float*)d_in[6];
    float* out = (float*)d_out;

    dim3 grid(NBLK * NN);   // 4096 workgroups: one per (block, batch)
    dim3 block(128);        // 2 rows per thread
    BlockCrossAttn_kernel<<<grid, block, 0, stream>>>(q, k, v, ipw, ipb, opw, opb, out);
}